// Round 3
// baseline (204.353 us; speedup 1.0000x reference)
//
#include <hip/hip_runtime.h>
#include <hip/hip_bf16.h>

// Tokenizer: masked row compaction — single fused dispatch.
//   inputs:  hidden_states (B,L,D) fp32, token_mask (B,L) int32 (0/1)
//   outputs: chunked (B,M,D) fp32 left-packed zero-padded, counts (B,) as floats
// d_out layout (flat fp32): [B*M*D chunked][B counts]
//
// Grid: B*256 blocks of 256 threads. Block (b, seg) redundantly scans row b's
// mask (16 KiB, L2-resident after first touch), derives the exclusive prefix
// for its own 16-element source segment, then copies those masked rows to
// their contiguous destination slots (contiguous source range -> contiguous
// dest range). Padding slots [count, M) are zero-filled strided across the
// 256 blocks of the row. No workspace, no inter-kernel dependency, no
// global pointer-chase for source indices.

__global__ __launch_bounds__(256) void fused_pack_kernel(
        const float4* __restrict__ hidden,
        const int* __restrict__ mask,
        float4* __restrict__ out,
        float* __restrict__ counts_out,
        int L, int M, int D4) {
    const int b   = blockIdx.x >> 8;     // 256 blocks per batch row
    const int seg = blockIdx.x & 255;
    const int t    = threadIdx.x;        // 0..255; thread t scans segment t
    const int lane = t & 63;
    const int wid  = t >> 6;             // 0..3

    // --- phase 1: full-row mask scan (each thread owns 16 elems) ---
    const int* mrow = mask + (size_t)b * L;
    const int4 v0 = *(const int4*)(mrow + t * 16 + 0);
    const int4 v1 = *(const int4*)(mrow + t * 16 + 4);
    const int4 v2 = *(const int4*)(mrow + t * 16 + 8);
    const int4 v3 = *(const int4*)(mrow + t * 16 + 12);
    int mm[16];
    mm[0]=(v0.x!=0); mm[1]=(v0.y!=0); mm[2]=(v0.z!=0); mm[3]=(v0.w!=0);
    mm[4]=(v1.x!=0); mm[5]=(v1.y!=0); mm[6]=(v1.z!=0); mm[7]=(v1.w!=0);
    mm[8]=(v2.x!=0); mm[9]=(v2.y!=0); mm[10]=(v2.z!=0); mm[11]=(v2.w!=0);
    mm[12]=(v3.x!=0); mm[13]=(v3.y!=0); mm[14]=(v3.z!=0); mm[15]=(v3.w!=0);
    int s = 0;
    #pragma unroll
    for (int i = 0; i < 16; ++i) s += mm[i];

    // wave-inclusive scan of per-thread sums
    int incl = s;
    #pragma unroll
    for (int off = 1; off < 64; off <<= 1) {
        int up = __shfl_up(incl, off, 64);
        if (lane >= off) incl += up;
    }

    __shared__ int wsum[4];
    __shared__ int woff[4];
    __shared__ int sh_total;
    __shared__ int sh_base;
    __shared__ int sh_n;
    __shared__ int sh_src[16];

    if (lane == 63) wsum[wid] = incl;
    __syncthreads();
    if (t == 0) {
        int acc = 0;
        #pragma unroll
        for (int w = 0; w < 4; ++w) { woff[w] = acc; acc += wsum[w]; }
        sh_total = acc;
    }
    __syncthreads();

    // exclusive prefix at this thread's segment start
    const int exc = woff[wid] + (incl - s);

    // thread whose segment == this block's segment publishes its source list
    if (t == seg) {
        sh_base = exc;
        int n = 0;
        #pragma unroll
        for (int i = 0; i < 16; ++i)
            if (mm[i]) sh_src[n++] = seg * 16 + i;
        sh_n = n;
    }
    __syncthreads();

    // --- phase 2: copy this segment's masked rows (1 float4/lane/row) ---
    const int n = sh_n;
    const int base = sh_base;
    const size_t hrow0 = (size_t)b * L;
    const size_t orow0 = (size_t)b * M;
    for (int j = 0; j < n; ++j) {
        const size_t irow = (hrow0 + sh_src[j]) * D4 + t;
        const size_t orow = (orow0 + base + j) * D4 + t;
        out[orow] = hidden[irow];
    }

    // --- phase 3: zero-fill padding slots, strided across the row's blocks ---
    const int total = sh_total;
    const float4 z = make_float4(0.f, 0.f, 0.f, 0.f);
    for (int m = total + seg; m < M; m += 256) {
        out[(orow0 + m) * D4 + t] = z;
    }

    if (seg == 0 && t == 0) counts_out[b] = (float)total;
}

extern "C" void kernel_launch(void* const* d_in, const int* in_sizes, int n_in,
                              void* d_out, int out_size, void* d_ws, size_t ws_size,
                              hipStream_t stream) {
    const int B = 8;                       // per setup_inputs()
    const int BL = in_sizes[1];            // B*L = 32768
    const int D  = in_sizes[0] / BL;       // 1024
    const int L  = BL / B;                 // 4096
    const int M  = (out_size - B) / (B * D);

    const float* hidden = (const float*)d_in[0];
    const int*   mask   = (const int*)d_in[1];
    float*       out    = (float*)d_out;
    float* counts_out = out + (size_t)B * M * D;

    if (M > 0) {
        fused_pack_kernel<<<B * 256, 256, 0, stream>>>(
            (const float4*)hidden, mask, (float4*)out, counts_out, L, M, D / 4);
    }
}